// Round 2
// baseline (795.245 us; speedup 1.0000x reference)
//
#include <hip/hip_runtime.h>

#define B_    32
#define NV    1556
#define NI    256
#define NT    1812          // NV + NI
#define D_    512
#define IMGD  2048
#define MV    (B_*NV)       // 49792 = 778*64
#define MI    (B_*NI)       // 8192  = 128*64
#define MQ    (B_*NT)       // 57984
#define SCALE_ 0.08838834764831845f   // (512/4)^-0.5

typedef _Float16 half_t;
typedef __attribute__((ext_vector_type(4))) _Float16 half4;
typedef __attribute__((ext_vector_type(8))) _Float16 half8;
typedef __attribute__((ext_vector_type(4))) float floatx4;

__device__ __forceinline__ void gload16(const void* g, void* l) {
    __builtin_amdgcn_global_load_lds(
        (const __attribute__((address_space(1))) void*)g,
        (__attribute__((address_space(3))) void*)l, 16, 0, 0);
}

// ---------------------------------------------------------------- convert
// fp32 -> f16: verts, img_f, fc_w, q_w, k_w, final_w (proj_w handled by transpose)
__global__ __launch_bounds__(256) void convert_all(
    const float* __restrict__ verts, const float* __restrict__ img,
    const float* __restrict__ w2, const float* __restrict__ w3,
    const float* __restrict__ w4, const float* __restrict__ w5,
    half_t* __restrict__ o0, half_t* __restrict__ o1, half_t* __restrict__ o2,
    half_t* __restrict__ o3, half_t* __restrict__ o4, half_t* __restrict__ o5)
{
    const long E0 = (long)MV * D_;
    const long E1 = (long)MI * IMGD;
    const long E2 = (long)D_ * IMGD;
    const long E3 = (long)D_ * D_;
    const long total4 = (E0 + E1 + E2 + 3 * E3) / 4;
    for (long i = blockIdx.x * (long)blockDim.x + threadIdx.x; i < total4;
         i += (long)gridDim.x * blockDim.x) {
        long e = i * 4;
        const float* s; half_t* d;
        if (e < E0)              { s = verts; d = o0; }
        else if ((e -= E0) < E1) { s = img;   d = o1; }
        else if ((e -= E1) < E2) { s = w2;    d = o2; }
        else if ((e -= E2) < E3) { s = w3;    d = o3; }
        else if ((e -= E3) < E3) { s = w4;    d = o4; }
        else                     { e -= E3; s = w5; d = o5; }
        float4 x = *(const float4*)(s + e);
        half4 h = { (half_t)x.x, (half_t)x.y, (half_t)x.z, (half_t)x.w };
        *(half4*)(d + e) = h;
    }
}

// pwt[d*512+e] = proj_w[e*512+d]  (f16)
__global__ __launch_bounds__(256) void transpose_pw(
    const float* __restrict__ P, half_t* __restrict__ pwt)
{
    const int n = blockIdx.x;            // output row (d index)
    for (int d = threadIdx.x; d < 512; d += 256)
        pwt[(size_t)n * 512 + d] = (half_t)P[(size_t)d * 512 + n];
}

// bias2[f] = sum_e pb[e]*F[f,e] + fb[f]
__global__ __launch_bounds__(256) void make_bias2(
    const float* __restrict__ pb, const float* __restrict__ F,
    const float* __restrict__ fb, float* __restrict__ bias2)
{
    const int n = blockIdx.x * 256 + threadIdx.x;
    float s = fb[n];
    for (int d = 0; d < 512; d++) s += pb[d] * F[(size_t)n * 512 + d];
    bias2[n] = s;
}

// ---------------------------------------------------------------- basic GEMM
// C[M,512] = A[M,K] @ Bw[512,K]^T (+bias if MODE==0), f16 store. 128x128 tiles.
template<int MODE>
__global__ __launch_bounds__(256) void gemm_bt(
    const half_t* __restrict__ A, const half_t* __restrict__ Bw,
    const float* __restrict__ bias, int K, half_t* __restrict__ Ch)
{
    __shared__ __align__(16) half_t As[128 * 32];
    __shared__ __align__(16) half_t Bs[128 * 32];
    const int tid  = threadIdx.x;
    const int lane = tid & 63;
    const int wave = tid >> 6;
    const int wr = (wave >> 1) * 64;
    const int wc = (wave & 1) * 64;
    const int bm = blockIdx.x, bn = blockIdx.y;

    floatx4 acc[4][4];
#pragma unroll
    for (int i = 0; i < 4; i++)
#pragma unroll
        for (int j = 0; j < 4; j++) acc[i][j] = (floatx4){0.f, 0.f, 0.f, 0.f};

    const int c0 = tid, c1 = tid + 256;
    const half_t* ag0 = A  + (size_t)(bm * 128 + (c0 >> 2)) * K + (c0 & 3) * 8;
    const half_t* ag1 = A  + (size_t)(bm * 128 + (c1 >> 2)) * K + (c1 & 3) * 8;
    const half_t* bg0 = Bw + (size_t)(bn * 128 + (c0 >> 2)) * K + (c0 & 3) * 8;
    const half_t* bg1 = Bw + (size_t)(bn * 128 + (c1 >> 2)) * K + (c1 & 3) * 8;
    half_t* al0 = &As[c0 * 8]; half_t* al1 = &As[c1 * 8];
    half_t* bl0 = &Bs[c0 * 8]; half_t* bl1 = &Bs[c1 * 8];
    const int fr = (lane & 15) * 32 + (lane >> 4) * 8;

    for (int k0 = 0; k0 < K; k0 += 32) {
        __syncthreads();
        gload16(ag0 + k0, al0);
        gload16(ag1 + k0, al1);
        gload16(bg0 + k0, bl0);
        gload16(bg1 + k0, bl1);
        __syncthreads();
        half8 a[4], b[4];
#pragma unroll
        for (int i = 0; i < 4; i++)
            a[i] = *(const half8*)&As[(wr + i * 16) * 32 + fr];
#pragma unroll
        for (int j = 0; j < 4; j++)
            b[j] = *(const half8*)&Bs[(wc + j * 16) * 32 + fr];
#pragma unroll
        for (int i = 0; i < 4; i++)
#pragma unroll
            for (int j = 0; j < 4; j++)
                acc[i][j] = __builtin_amdgcn_mfma_f32_16x16x32_f16(
                    a[i], b[j], acc[i][j], 0, 0, 0);
    }

    const int colbase = bn * 128 + wc + (lane & 15);
    const int rowbase = bm * 128 + wr + ((lane >> 4) << 2);
#pragma unroll
    for (int i = 0; i < 4; i++)
#pragma unroll
        for (int j = 0; j < 4; j++) {
            const int col = colbase + j * 16;
            const float bv = (MODE == 0) ? bias[col] : 0.f;
#pragma unroll
            for (int r = 0; r < 4; r++) {
                const int grow = rowbase + i * 16 + r;
                Ch[(size_t)grow * D_ + col] = (half_t)(acc[i][j][r] + bv);
            }
        }
}

// ---------------------------------------------------------------- fused q(+k) GEMM with l2norm
// Block: 64 rows x 512 cols. Wave w: cols [w*128, w*128+128). Fuses bias,
// row-l2norm, w_g logits (q), and writes f16. Optional second pass for k.
template<int TA, int COFF, bool DO_K>
__global__ __launch_bounds__(256, 2) void qk_fused(
    const half_t* __restrict__ A, const half_t* __restrict__ Qw,
    const half_t* __restrict__ Kw,
    const float* __restrict__ q_bias, const float* __restrict__ k_bias,
    const float* __restrict__ wg,
    half_t* __restrict__ qout, half_t* __restrict__ kout,
    float* __restrict__ araw)
{
    __shared__ __align__(16) half_t As[64 * 32];     // 4 KB
    __shared__ __align__(16) half_t Bs[512 * 32];    // 32 KB
    __shared__ float red_l[4][64];
    __shared__ float scale_l[64];

    const int tid = threadIdx.x, lane = tid & 63, wave = tid >> 6;
    const int bm = blockIdx.x;
    const int wc = wave * 128;

    const half_t* ag = A + (size_t)(bm * 64 + (tid >> 2)) * 512 + (tid & 3) * 8;
    half_t* al = &As[tid * 8];
    size_t boff[8];
#pragma unroll
    for (int s = 0; s < 8; s++)
        boff[s] = (size_t)((tid >> 2) + 64 * s) * 512 + (tid & 3) * 8;
    const int fr_k = (lane >> 4) * 8;

    const int nphase = DO_K ? 2 : 1;
    for (int phase = 0; phase < nphase; phase++) {
        const half_t* Bw = (phase == 0) ? Qw : Kw;
        floatx4 acc[4][8];
#pragma unroll
        for (int i = 0; i < 4; i++)
#pragma unroll
            for (int j = 0; j < 8; j++) acc[i][j] = (floatx4){0.f, 0.f, 0.f, 0.f};

        for (int k0 = 0; k0 < 512; k0 += 32) {
            __syncthreads();
            gload16(ag + k0, al);
#pragma unroll
            for (int s = 0; s < 8; s++)
                gload16(Bw + boff[s] + k0, &Bs[(tid + 256 * s) * 8]);
            __syncthreads();
            half8 a[4], b[8];
#pragma unroll
            for (int i = 0; i < 4; i++)
                a[i] = *(const half8*)&As[(i * 16 + (lane & 15)) * 32 + fr_k];
#pragma unroll
            for (int j = 0; j < 8; j++)
                b[j] = *(const half8*)&Bs[(wc + j * 16 + (lane & 15)) * 32 + fr_k];
#pragma unroll
            for (int i = 0; i < 4; i++)
#pragma unroll
                for (int j = 0; j < 8; j++)
                    acc[i][j] = __builtin_amdgcn_mfma_f32_16x16x32_f16(
                        a[i], b[j], acc[i][j], 0, 0, 0);
        }

        // ---- epilogue: bias + row sum-of-squares
        const float* bias = (phase == 0) ? q_bias : k_bias;
        float ssq[4][4];
#pragma unroll
        for (int i = 0; i < 4; i++)
#pragma unroll
            for (int r = 0; r < 4; r++) ssq[i][r] = 0.f;
#pragma unroll
        for (int j = 0; j < 8; j++) {
            const float bv = bias[wc + j * 16 + (lane & 15)];
#pragma unroll
            for (int i = 0; i < 4; i++)
#pragma unroll
                for (int r = 0; r < 4; r++) {
                    float v = acc[i][j][r] + bv;
                    acc[i][j][r] = v;
                    ssq[i][r] += v * v;
                }
        }
#pragma unroll
        for (int i = 0; i < 4; i++)
#pragma unroll
            for (int r = 0; r < 4; r++)
#pragma unroll
                for (int m = 1; m < 16; m <<= 1)
                    ssq[i][r] += __shfl_xor(ssq[i][r], m, 64);
        if ((lane & 15) == 0) {
#pragma unroll
            for (int i = 0; i < 4; i++)
#pragma unroll
                for (int r = 0; r < 4; r++)
                    red_l[wave][i * 16 + (lane >> 4) * 4 + r] = ssq[i][r];
        }
        __syncthreads();
        if (tid < 64)
            scale_l[tid] = 1.f / fmaxf(
                sqrtf(red_l[0][tid] + red_l[1][tid] + red_l[2][tid] + red_l[3][tid]),
                1e-12f);
        __syncthreads();
        float sc[4][4];
#pragma unroll
        for (int i = 0; i < 4; i++)
#pragma unroll
            for (int r = 0; r < 4; r++)
                sc[i][r] = scale_l[i * 16 + (lane >> 4) * 4 + r];

        if (phase == 0) {
            // normalized write (remapped) + logits
            int qoff[4][4];
#pragma unroll
            for (int i = 0; i < 4; i++)
#pragma unroll
                for (int r = 0; r < 4; r++) {
                    const int gr = bm * 64 + i * 16 + (lane >> 4) * 4 + r;
                    const int b = gr / TA, t = gr - b * TA;
                    qoff[i][r] = (b * NT + COFF + t) * 512;
                }
            float dot[4][4];
#pragma unroll
            for (int i = 0; i < 4; i++)
#pragma unroll
                for (int r = 0; r < 4; r++) dot[i][r] = 0.f;
#pragma unroll
            for (int j = 0; j < 8; j++) {
                const int col = wc + j * 16 + (lane & 15);
                const float wgv = wg[col];
#pragma unroll
                for (int i = 0; i < 4; i++)
#pragma unroll
                    for (int r = 0; r < 4; r++) {
                        float qn = acc[i][j][r] * sc[i][r];
                        qout[(size_t)qoff[i][r] + col] = (half_t)qn;
                        dot[i][r] += qn * wgv;
                    }
            }
#pragma unroll
            for (int i = 0; i < 4; i++)
#pragma unroll
                for (int r = 0; r < 4; r++)
#pragma unroll
                    for (int m = 1; m < 16; m <<= 1)
                        dot[i][r] += __shfl_xor(dot[i][r], m, 64);
            if ((lane & 15) == 0) {
#pragma unroll
                for (int i = 0; i < 4; i++)
#pragma unroll
                    for (int r = 0; r < 4; r++)
                        red_l[wave][i * 16 + (lane >> 4) * 4 + r] = dot[i][r];
            }
            __syncthreads();
            if (tid < 64) {
                const int gr = bm * 64 + tid;
                const int b = gr / TA, t = gr - b * TA;
                araw[b * NT + COFF + t] = SCALE_ *
                    (red_l[0][tid] + red_l[1][tid] + red_l[2][tid] + red_l[3][tid]);
            }
        } else {
            // normalized k write (global vert rows)
#pragma unroll
            for (int j = 0; j < 8; j++) {
                const int col = wc + j * 16 + (lane & 15);
#pragma unroll
                for (int i = 0; i < 4; i++)
#pragma unroll
                    for (int r = 0; r < 4; r++) {
                        const int gr = bm * 64 + i * 16 + (lane >> 4) * 4 + r;
                        kout[(size_t)gr * 512 + col] = (half_t)(acc[i][j][r] * sc[i][r]);
                    }
            }
        }
    }
}

// ---------------------------------------------------------------- softmax (per batch) + zero g
__global__ __launch_bounds__(256) void softmax_w(
    float* __restrict__ araw, float* __restrict__ g)
{
    const int b = blockIdx.x;
    float* a = araw + (size_t)b * NT;
    g[b * D_ + threadIdx.x] = 0.f;
    g[b * D_ + 256 + threadIdx.x] = 0.f;
    __shared__ float red[8];
    const int lane = threadIdx.x & 63, wave = threadIdx.x >> 6;
    float m = -1e30f;
    for (int i = threadIdx.x; i < NT; i += 256) m = fmaxf(m, a[i]);
#pragma unroll
    for (int off = 32; off > 0; off >>= 1) m = fmaxf(m, __shfl_xor(m, off, 64));
    if (lane == 0) red[wave] = m;
    __syncthreads();
    m = fmaxf(fmaxf(red[0], red[1]), fmaxf(red[2], red[3]));
    float s = 0.f;
    for (int i = threadIdx.x; i < NT; i += 256) s += expf(a[i] - m);
#pragma unroll
    for (int off = 32; off > 0; off >>= 1) s += __shfl_xor(s, off, 64);
    if (lane == 0) red[4 + wave] = s;
    __syncthreads();
    s = red[4] + red[5] + red[6] + red[7];
    const float inv = 1.0f / s;
    for (int i = threadIdx.x; i < NT; i += 256) a[i] = expf(a[i] - m) * inv;
}

// ---------------------------------------------------------------- g = sum_n a_n * q_n  (vectorized)
__global__ __launch_bounds__(256) void accum_g(
    const float* __restrict__ w, const half_t* __restrict__ qb, float* __restrict__ g)
{
    __shared__ float red[4][512];
    const int b = blockIdx.y, tid = threadIdx.x, lane = tid & 63, wave = tid >> 6;
    const int t0 = blockIdx.x * 227;
    const int t1 = (t0 + 227 < NT) ? t0 + 227 : NT;
    float a[8];
#pragma unroll
    for (int r = 0; r < 8; r++) a[r] = 0.f;
    for (int n = t0 + wave; n < t1; n += 4) {
        const float wn = w[(size_t)b * NT + n];
        half8 v = *(const half8*)&qb[((size_t)b * NT + n) * 512 + lane * 8];
#pragma unroll
        for (int r = 0; r < 8; r++) a[r] += wn * (float)v[r];
    }
#pragma unroll
    for (int r = 0; r < 8; r++) red[wave][lane * 8 + r] = a[r];
    __syncthreads();
    for (int d = tid; d < 512; d += 256)
        atomicAdd(&g[b * 512 + d], red[0][d] + red[1][d] + red[2][d] + red[3][d]);
}

// ---------------------------------------------------------------- W2b[b][f,d] = W2[f,d]*g[b,d]
__global__ __launch_bounds__(256) void make_w2b(
    const half_t* __restrict__ w2, const float* __restrict__ g, half_t* __restrict__ w2b)
{
    const size_t h = (size_t)blockIdx.x * 256 + threadIdx.x;   // < 1048576
    const int k8 = (int)(h & 63);
    const int n  = (int)((h >> 6) & 511);
    const int b  = (int)(h >> 15);
    half8 v = *(const half8*)&w2[(size_t)n * 512 + k8 * 8];
    const float* gp = &g[b * 512 + k8 * 8];
    half8 o;
#pragma unroll
    for (int r = 0; r < 8; r++) o[r] = (half_t)((float)v[r] * gp[r]);
    *(half8*)&w2b[h * 8] = o;
}

// ---------------------------------------------------------------- final fused GEMM
// out[b,t,f] = verts + bias2[f] + sum_d knorm[b,t,d]*W2b[b][f,d]
//                               + sum_e qnorm[b,t,e]*F[f,e]
__global__ __launch_bounds__(256) void final2(
    const half_t* __restrict__ kb, const half_t* __restrict__ qb,
    const half_t* __restrict__ W2b, const half_t* __restrict__ Fw,
    const float* __restrict__ bias2, const float* __restrict__ verts,
    float* __restrict__ out)
{
    __shared__ __align__(16) half_t As[128 * 32];
    __shared__ __align__(16) half_t Bs[128 * 32];
    const int tid  = threadIdx.x;
    const int lane = tid & 63;
    const int wave = tid >> 6;
    const int wr = (wave >> 1) * 64;
    const int wc = (wave & 1) * 64;
    const int bm = blockIdx.x, bn = blockIdx.y, b = blockIdx.z;

    floatx4 acc[4][4];
#pragma unroll
    for (int i = 0; i < 4; i++)
#pragma unroll
        for (int j = 0; j < 4; j++) acc[i][j] = (floatx4){0.f, 0.f, 0.f, 0.f};

    const int c0 = tid, c1 = tid + 256;
    int t0c = bm * 128 + (c0 >> 2); if (t0c >= NV) t0c = NV - 1;
    int t1c = bm * 128 + (c1 >> 2); if (t1c >= NV) t1c = NV - 1;
    half_t* al0 = &As[c0 * 8]; half_t* al1 = &As[c1 * 8];
    half_t* bl0 = &Bs[c0 * 8]; half_t* bl1 = &Bs[c1 * 8];
    const int fr = (lane & 15) * 32 + (lane >> 4) * 8;

    for (int phase = 0; phase < 2; phase++) {
        const half_t* A = phase ? qb : kb;
        const size_t rowstart = phase ? (size_t)b * NT : (size_t)b * NV;
        const half_t* Bw = phase ? Fw : (W2b + (size_t)b * 512 * 512);
        const half_t* ag0 = A + (rowstart + t0c) * 512 + (c0 & 3) * 8;
        const half_t* ag1 = A + (rowstart + t1c) * 512 + (c1 & 3) * 8;
        const half_t* bg0 = Bw + (size_t)(bn * 128 + (c0 >> 2)) * 512 + (c0 & 3) * 8;
        const half_t* bg1 = Bw + (size_t)(bn * 128 + (c1 >> 2)) * 512 + (c1 & 3) * 8;

        for (int k0 = 0; k0 < 512; k0 += 32) {
            __syncthreads();
            gload16(ag0 + k0, al0);
            gload16(ag1 + k0, al1);
            gload16(bg0 + k0, bl0);
            gload16(bg1 + k0, bl1);
            __syncthreads();
            half8 a[4], bfr[4];
#pragma unroll
            for (int i = 0; i < 4; i++)
                a[i] = *(const half8*)&As[(wr + i * 16) * 32 + fr];
#pragma unroll
            for (int j = 0; j < 4; j++)
                bfr[j] = *(const half8*)&Bs[(wc + j * 16) * 32 + fr];
#pragma unroll
            for (int i = 0; i < 4; i++)
#pragma unroll
                for (int j = 0; j < 4; j++)
                    acc[i][j] = __builtin_amdgcn_mfma_f32_16x16x32_f16(
                        a[i], bfr[j], acc[i][j], 0, 0, 0);
        }
    }

    const int colbase = bn * 128 + wc + (lane & 15);
    const int rowbase = bm * 128 + wr + ((lane >> 4) << 2);
#pragma unroll
    for (int i = 0; i < 4; i++)
#pragma unroll
        for (int j = 0; j < 4; j++) {
            const int col = colbase + j * 16;
            const float bv = bias2[col];
#pragma unroll
            for (int r = 0; r < 4; r++) {
                const int t = rowbase + i * 16 + r;
                if (t < NV) {
                    const size_t idx = ((size_t)b * NV + t) * 512 + col;
                    out[idx] = acc[i][j][r] + bv + verts[idx];
                }
            }
        }
}

// ---------------------------------------------------------------- launch
extern "C" void kernel_launch(void* const* d_in, const int* in_sizes, int n_in,
                              void* d_out, int out_size, void* d_ws, size_t ws_size,
                              hipStream_t stream)
{
    const float* verts  = (const float*)d_in[0];
    const float* imgf   = (const float*)d_in[1];
    const float* fc_w   = (const float*)d_in[2];
    const float* fc_b   = (const float*)d_in[3];
    const float* q_w    = (const float*)d_in[4];
    const float* q_b    = (const float*)d_in[5];
    const float* k_w    = (const float*)d_in[6];
    const float* k_b    = (const float*)d_in[7];
    const float* w_g    = (const float*)d_in[8];
    const float* proj_w = (const float*)d_in[9];
    const float* proj_b = (const float*)d_in[10];
    const float* fin_w  = (const float*)d_in[11];
    const float* fin_b  = (const float*)d_in[12];

    char* ws = (char*)d_ws;
    size_t off = 0;
    auto alloc = [&](size_t bytes) -> void* {
        void* p = ws + off;
        off += (bytes + 255) & ~(size_t)255;
        return p;
    };
    half_t* vb    = (half_t*)alloc((size_t)MV * D_ * 2);
    half_t* ib    = (half_t*)alloc((size_t)MI * IMGD * 2);
    half_t* fcwb  = (half_t*)alloc((size_t)D_ * IMGD * 2);
    half_t* qwb   = (half_t*)alloc((size_t)D_ * D_ * 2);
    half_t* kwb   = (half_t*)alloc((size_t)D_ * D_ * 2);
    half_t* fwb   = (half_t*)alloc((size_t)D_ * D_ * 2);
    half_t* pwtb  = (half_t*)alloc((size_t)D_ * D_ * 2);
    half_t* w2    = (half_t*)alloc((size_t)D_ * D_ * 2);
    half_t* w2b   = (half_t*)alloc((size_t)B_ * D_ * D_ * 2);
    half_t* imgp  = (half_t*)alloc((size_t)MI * D_ * 2);
    half_t* qb    = (half_t*)alloc((size_t)MQ * D_ * 2);
    half_t* kb    = (half_t*)alloc((size_t)MV * D_ * 2);
    float*  araw  = (float*)alloc((size_t)MQ * 4);
    float*  g     = (float*)alloc((size_t)B_ * D_ * 4);
    float*  bias2 = (float*)alloc((size_t)D_ * 4);

    convert_all<<<4096, 256, 0, stream>>>(verts, imgf, fc_w, q_w, k_w, fin_w,
                                          vb, ib, fcwb, qwb, kwb, fwb);
    transpose_pw<<<512, 256, 0, stream>>>(proj_w, pwtb);
    make_bias2<<<2, 256, 0, stream>>>(proj_b, fin_w, fin_b, bias2);
    // W2 = F @ P : [512,512]
    gemm_bt<4><<<dim3(4, 4), 256, 0, stream>>>(fwb, pwtb, nullptr, D_, w2);
    // imgp = img_f @ fc_w^T + fc_b
    gemm_bt<0><<<dim3(MI / 128, 4), 256, 0, stream>>>(ib, fcwb, fc_b, IMGD, imgp);
    // q+k fused over vert rows (norms + logits in-epilogue)
    qk_fused<NV, 0, true><<<MV / 64, 256, 0, stream>>>(
        vb, qwb, kwb, q_b, k_b, w_g, qb, kb, araw);
    // q only over img rows
    qk_fused<NI, NV, false><<<MI / 64, 256, 0, stream>>>(
        imgp, qwb, nullptr, q_b, nullptr, w_g, qb, nullptr, araw);
    softmax_w<<<B_, 256, 0, stream>>>(araw, g);
    accum_g<<<dim3(8, B_), 256, 0, stream>>>(araw, qb, g);
    make_w2b<<<4096, 256, 0, stream>>>(w2, g, w2b);
    // out = verts + bias2 + knorm @ W2b^T + qnorm @ F^T
    final2<<<dim3(13, 4, B_), 256, 0, stream>>>(
        kb, qb, w2b, fwb, bias2, verts, (float*)d_out);
}

// Round 3
// 639.936 us; speedup vs baseline: 1.2427x; 1.2427x over previous
//
#include <hip/hip_runtime.h>

#define B_    32
#define NV    1556
#define NI    256
#define NT    1812          // NV + NI
#define D_    512
#define IMGD  2048
#define MV    (B_*NV)       // 49792 = 778*64
#define MI    (B_*NI)       // 8192  = 128*64
#define MQ    (B_*NT)       // 57984
#define SCALE_ 0.08838834764831845f   // (512/4)^-0.5

typedef _Float16 half_t;
typedef __attribute__((ext_vector_type(4))) _Float16 half4;
typedef __attribute__((ext_vector_type(8))) _Float16 half8;
typedef __attribute__((ext_vector_type(4))) float floatx4;

__device__ __forceinline__ void gload16(const void* g, void* l) {
    __builtin_amdgcn_global_load_lds(
        (const __attribute__((address_space(1))) void*)g,
        (__attribute__((address_space(3))) void*)l, 16, 0, 0);
}

// ---------------------------------------------------------------- convert
// fp32 -> f16: verts, img_f, fc_w, q_w, k_w, final_w (proj_w handled by transpose)
__global__ __launch_bounds__(256) void convert_all(
    const float* __restrict__ verts, const float* __restrict__ img,
    const float* __restrict__ w2, const float* __restrict__ w3,
    const float* __restrict__ w4, const float* __restrict__ w5,
    half_t* __restrict__ o0, half_t* __restrict__ o1, half_t* __restrict__ o2,
    half_t* __restrict__ o3, half_t* __restrict__ o4, half_t* __restrict__ o5)
{
    const long E0 = (long)MV * D_;
    const long E1 = (long)MI * IMGD;
    const long E2 = (long)D_ * IMGD;
    const long E3 = (long)D_ * D_;
    const long total4 = (E0 + E1 + E2 + 3 * E3) / 4;
    for (long i = blockIdx.x * (long)blockDim.x + threadIdx.x; i < total4;
         i += (long)gridDim.x * blockDim.x) {
        long e = i * 4;
        const float* s; half_t* d;
        if (e < E0)              { s = verts; d = o0; }
        else if ((e -= E0) < E1) { s = img;   d = o1; }
        else if ((e -= E1) < E2) { s = w2;    d = o2; }
        else if ((e -= E2) < E3) { s = w3;    d = o3; }
        else if ((e -= E3) < E3) { s = w4;    d = o4; }
        else                     { e -= E3; s = w5; d = o5; }
        float4 x = *(const float4*)(s + e);
        half4 h = { (half_t)x.x, (half_t)x.y, (half_t)x.z, (half_t)x.w };
        *(half4*)(d + e) = h;
    }
}

// pwt[d,e] = proj_w[e,d]  (f16)  -> Bw operand for W2 = F @ P
__global__ __launch_bounds__(256) void transpose_pw(
    const float* __restrict__ P, half_t* __restrict__ pwt)
{
    const int n = blockIdx.x;
    for (int d = threadIdx.x; d < 512; d += 256)
        pwt[(size_t)n * 512 + d] = (half_t)P[(size_t)d * 512 + n];
}

// bias2[f] = sum_d pb[d]*F[f,d] + fb[f]
__global__ __launch_bounds__(256) void make_bias2(
    const float* __restrict__ pb, const float* __restrict__ F,
    const float* __restrict__ fb, float* __restrict__ bias2)
{
    const int n = blockIdx.x * 256 + threadIdx.x;
    float s = fb[n];
    for (int d = 0; d < 512; d++) s += pb[d] * F[(size_t)n * 512 + d];
    bias2[n] = s;
}

// ---------------------------------------------------------------- basic GEMM
// C[M,512] = A[M,K] @ Bw[512,K]^T (+bias if MODE==0), f16 store. 128x128 tiles.
template<int MODE>
__global__ __launch_bounds__(256) void gemm_bt(
    const half_t* __restrict__ A, const half_t* __restrict__ Bw,
    const float* __restrict__ bias, int K, half_t* __restrict__ Ch)
{
    __shared__ __align__(16) half_t As[128 * 32];
    __shared__ __align__(16) half_t Bs[128 * 32];
    const int tid  = threadIdx.x;
    const int lane = tid & 63;
    const int wave = tid >> 6;
    const int wr = (wave >> 1) * 64;
    const int wc = (wave & 1) * 64;
    const int bm = blockIdx.x, bn = blockIdx.y;

    floatx4 acc[4][4];
#pragma unroll
    for (int i = 0; i < 4; i++)
#pragma unroll
        for (int j = 0; j < 4; j++) acc[i][j] = (floatx4){0.f, 0.f, 0.f, 0.f};

    const int c0 = tid, c1 = tid + 256;
    const half_t* ag0 = A  + (size_t)(bm * 128 + (c0 >> 2)) * K + (c0 & 3) * 8;
    const half_t* ag1 = A  + (size_t)(bm * 128 + (c1 >> 2)) * K + (c1 & 3) * 8;
    const half_t* bg0 = Bw + (size_t)(bn * 128 + (c0 >> 2)) * K + (c0 & 3) * 8;
    const half_t* bg1 = Bw + (size_t)(bn * 128 + (c1 >> 2)) * K + (c1 & 3) * 8;
    half_t* al0 = &As[c0 * 8]; half_t* al1 = &As[c1 * 8];
    half_t* bl0 = &Bs[c0 * 8]; half_t* bl1 = &Bs[c1 * 8];
    const int fr = (lane & 15) * 32 + (lane >> 4) * 8;

    for (int k0 = 0; k0 < K; k0 += 32) {
        __syncthreads();
        gload16(ag0 + k0, al0);
        gload16(ag1 + k0, al1);
        gload16(bg0 + k0, bl0);
        gload16(bg1 + k0, bl1);
        __syncthreads();
        half8 a[4], b[4];
#pragma unroll
        for (int i = 0; i < 4; i++)
            a[i] = *(const half8*)&As[(wr + i * 16) * 32 + fr];
#pragma unroll
        for (int j = 0; j < 4; j++)
            b[j] = *(const half8*)&Bs[(wc + j * 16) * 32 + fr];
#pragma unroll
        for (int i = 0; i < 4; i++)
#pragma unroll
            for (int j = 0; j < 4; j++)
                acc[i][j] = __builtin_amdgcn_mfma_f32_16x16x32_f16(
                    a[i], b[j], acc[i][j], 0, 0, 0);
    }

    const int colbase = bn * 128 + wc + (lane & 15);
    const int rowbase = bm * 128 + wr + ((lane >> 4) << 2);
#pragma unroll
    for (int i = 0; i < 4; i++)
#pragma unroll
        for (int j = 0; j < 4; j++) {
            const int col = colbase + j * 16;
            const float bv = (MODE == 0) ? bias[col] : 0.f;
#pragma unroll
            for (int r = 0; r < 4; r++) {
                const int grow = rowbase + i * 16 + r;
                Ch[(size_t)grow * D_ + col] = (half_t)(acc[i][j][r] + bv);
            }
        }
}

// ---------------------------------------------------------------- fused GEMM + row l2norm
// Block: 64 rows x 512 cols (full N in-block so the row norm is local).
// MODE 0 (q): normalize, write remapped to [B,NT,D], compute w_g logits -> araw.
// MODE 1 (kg): normalize, multiply by g[b,col], write compact [MV,D].
template<int MODE, int TA, int COFF>
__global__ __launch_bounds__(256, 2) void nrm_gemm(
    const half_t* __restrict__ A, const half_t* __restrict__ Bw,
    const float* __restrict__ bias, const float* __restrict__ wg_or_g,
    half_t* __restrict__ outp, float* __restrict__ araw)
{
    __shared__ __align__(16) half_t As[64 * 32];     // 4 KB
    __shared__ __align__(16) half_t Bs[512 * 32];    // 32 KB
    __shared__ float red_l[4][64];
    __shared__ float scale_l[64];

    const int tid = threadIdx.x, lane = tid & 63, wave = tid >> 6;
    const int bm = blockIdx.x;
    const int wc = wave * 128;

    const half_t* ag = A + (size_t)(bm * 64 + (tid >> 2)) * 512 + (tid & 3) * 8;
    half_t* al = &As[tid * 8];
    size_t boff[8];
#pragma unroll
    for (int s = 0; s < 8; s++)
        boff[s] = (size_t)((tid >> 2) + 64 * s) * 512 + (tid & 3) * 8;
    const int fr_k = (lane >> 4) * 8;

    floatx4 acc[4][8];
#pragma unroll
    for (int i = 0; i < 4; i++)
#pragma unroll
        for (int j = 0; j < 8; j++) acc[i][j] = (floatx4){0.f, 0.f, 0.f, 0.f};

    for (int k0 = 0; k0 < 512; k0 += 32) {
        __syncthreads();
        gload16(ag + k0, al);
#pragma unroll
        for (int s = 0; s < 8; s++)
            gload16(Bw + boff[s] + k0, &Bs[(tid + 256 * s) * 8]);
        __syncthreads();
        half8 a[4], b[8];
#pragma unroll
        for (int i = 0; i < 4; i++)
            a[i] = *(const half8*)&As[(i * 16 + (lane & 15)) * 32 + fr_k];
#pragma unroll
        for (int j = 0; j < 8; j++)
            b[j] = *(const half8*)&Bs[(wc + j * 16 + (lane & 15)) * 32 + fr_k];
#pragma unroll
        for (int i = 0; i < 4; i++)
#pragma unroll
            for (int j = 0; j < 8; j++)
                acc[i][j] = __builtin_amdgcn_mfma_f32_16x16x32_f16(
                    a[i], b[j], acc[i][j], 0, 0, 0);
    }

    // ---- bias + row sum-of-squares
    float ssq[4][4];
#pragma unroll
    for (int i = 0; i < 4; i++)
#pragma unroll
        for (int r = 0; r < 4; r++) ssq[i][r] = 0.f;
#pragma unroll
    for (int j = 0; j < 8; j++) {
        const float bv = bias[wc + j * 16 + (lane & 15)];
#pragma unroll
        for (int i = 0; i < 4; i++)
#pragma unroll
            for (int r = 0; r < 4; r++) {
                float v = acc[i][j][r] + bv;
                acc[i][j][r] = v;
                ssq[i][r] += v * v;
            }
    }
#pragma unroll
    for (int i = 0; i < 4; i++)
#pragma unroll
        for (int r = 0; r < 4; r++)
#pragma unroll
            for (int m = 1; m < 16; m <<= 1)
                ssq[i][r] += __shfl_xor(ssq[i][r], m, 64);
    if ((lane & 15) == 0) {
#pragma unroll
        for (int i = 0; i < 4; i++)
#pragma unroll
            for (int r = 0; r < 4; r++)
                red_l[wave][i * 16 + (lane >> 4) * 4 + r] = ssq[i][r];
    }
    __syncthreads();
    if (tid < 64)
        scale_l[tid] = 1.f / fmaxf(
            sqrtf(red_l[0][tid] + red_l[1][tid] + red_l[2][tid] + red_l[3][tid]),
            1e-12f);
    __syncthreads();
    float sc[4][4];
    int rowb[4][4];   // batch index per row
#pragma unroll
    for (int i = 0; i < 4; i++)
#pragma unroll
        for (int r = 0; r < 4; r++) {
            const int li = i * 16 + (lane >> 4) * 4 + r;
            sc[i][r] = scale_l[li];
            rowb[i][r] = (bm * 64 + li) / TA;
        }

    if (MODE == 0) {
        int qoff[4][4];
#pragma unroll
        for (int i = 0; i < 4; i++)
#pragma unroll
            for (int r = 0; r < 4; r++) {
                const int gr = bm * 64 + i * 16 + (lane >> 4) * 4 + r;
                const int b = rowb[i][r], t = gr - b * TA;
                qoff[i][r] = (b * NT + COFF + t) * 512;
            }
        float dot[4][4];
#pragma unroll
        for (int i = 0; i < 4; i++)
#pragma unroll
            for (int r = 0; r < 4; r++) dot[i][r] = 0.f;
#pragma unroll
        for (int j = 0; j < 8; j++) {
            const int col = wc + j * 16 + (lane & 15);
            const float wgv = wg_or_g[col];
#pragma unroll
            for (int i = 0; i < 4; i++)
#pragma unroll
                for (int r = 0; r < 4; r++) {
                    float qn = acc[i][j][r] * sc[i][r];
                    outp[(size_t)qoff[i][r] + col] = (half_t)qn;
                    dot[i][r] += qn * wgv;
                }
        }
#pragma unroll
        for (int i = 0; i < 4; i++)
#pragma unroll
            for (int r = 0; r < 4; r++)
#pragma unroll
                for (int m = 1; m < 16; m <<= 1)
                    dot[i][r] += __shfl_xor(dot[i][r], m, 64);
        if ((lane & 15) == 0) {
#pragma unroll
            for (int i = 0; i < 4; i++)
#pragma unroll
                for (int r = 0; r < 4; r++)
                    red_l[wave][i * 16 + (lane >> 4) * 4 + r] = dot[i][r];
        }
        __syncthreads();
        if (tid < 64) {
            const int gr = bm * 64 + tid;
            const int b = gr / TA, t = gr - b * TA;
            araw[b * NT + COFF + t] = SCALE_ *
                (red_l[0][tid] + red_l[1][tid] + red_l[2][tid] + red_l[3][tid]);
        }
    } else {
        // kg = l2norm(k) * g[b, col], compact [MV, 512]
#pragma unroll
        for (int j = 0; j < 8; j++) {
            const int col = wc + j * 16 + (lane & 15);
#pragma unroll
            for (int i = 0; i < 4; i++)
#pragma unroll
                for (int r = 0; r < 4; r++) {
                    const int gr = bm * 64 + i * 16 + (lane >> 4) * 4 + r;
                    const float gv = wg_or_g[rowb[i][r] * 512 + col];
                    outp[(size_t)gr * 512 + col] =
                        (half_t)(acc[i][j][r] * sc[i][r] * gv);
                }
        }
    }
}

// ---------------------------------------------------------------- softmax (per batch) + zero g
__global__ __launch_bounds__(256) void softmax_w(
    float* __restrict__ araw, float* __restrict__ g)
{
    const int b = blockIdx.x;
    float* a = araw + (size_t)b * NT;
    g[b * D_ + threadIdx.x] = 0.f;
    g[b * D_ + 256 + threadIdx.x] = 0.f;
    __shared__ float red[8];
    const int lane = threadIdx.x & 63, wave = threadIdx.x >> 6;
    float m = -1e30f;
    for (int i = threadIdx.x; i < NT; i += 256) m = fmaxf(m, a[i]);
#pragma unroll
    for (int off = 32; off > 0; off >>= 1) m = fmaxf(m, __shfl_xor(m, off, 64));
    if (lane == 0) red[wave] = m;
    __syncthreads();
    m = fmaxf(fmaxf(red[0], red[1]), fmaxf(red[2], red[3]));
    float s = 0.f;
    for (int i = threadIdx.x; i < NT; i += 256) s += expf(a[i] - m);
#pragma unroll
    for (int off = 32; off > 0; off >>= 1) s += __shfl_xor(s, off, 64);
    if (lane == 0) red[4 + wave] = s;
    __syncthreads();
    s = red[4] + red[5] + red[6] + red[7];
    const float inv = 1.0f / s;
    for (int i = threadIdx.x; i < NT; i += 256) a[i] = expf(a[i] - m) * inv;
}

// ---------------------------------------------------------------- g = sum_n a_n * q_n
__global__ __launch_bounds__(256) void accum_g(
    const float* __restrict__ w, const half_t* __restrict__ qb, float* __restrict__ g)
{
    __shared__ float red[4][512];
    const int b = blockIdx.y, tid = threadIdx.x, lane = tid & 63, wave = tid >> 6;
    const int t0 = blockIdx.x * 227;
    const int t1 = (t0 + 227 < NT) ? t0 + 227 : NT;
    float a[8];
#pragma unroll
    for (int r = 0; r < 8; r++) a[r] = 0.f;
    for (int n = t0 + wave; n < t1; n += 4) {
        const float wn = w[(size_t)b * NT + n];
        half8 v = *(const half8*)&qb[((size_t)b * NT + n) * 512 + lane * 8];
#pragma unroll
        for (int r = 0; r < 8; r++) a[r] += wn * (float)v[r];
    }
#pragma unroll
    for (int r = 0; r < 8; r++) red[wave][lane * 8 + r] = a[r];
    __syncthreads();
    for (int d = tid; d < 512; d += 256)
        atomicAdd(&g[b * 512 + d], red[0][d] + red[1][d] + red[2][d] + red[3][d]);
}

// ---------------------------------------------------------------- final fused GEMM
// out[b,t,f] = vb[b,t,f] + bias2[f] + sum_d kg[b,t,d]*W2[f,d] + sum_e q[b,t,e]*F[f,e]
// W2 and F are shared across all batches (L2-resident).
__global__ __launch_bounds__(256) void final2(
    const half_t* __restrict__ kg, const half_t* __restrict__ qb,
    const half_t* __restrict__ W2, const half_t* __restrict__ Fw,
    const float* __restrict__ bias2, const half_t* __restrict__ vres,
    float* __restrict__ out)
{
    __shared__ __align__(16) half_t As[128 * 32];
    __shared__ __align__(16) half_t Bs[128 * 32];
    const int tid  = threadIdx.x;
    const int lane = tid & 63;
    const int wave = tid >> 6;
    const int wr = (wave >> 1) * 64;
    const int wc = (wave & 1) * 64;
    const int bm = blockIdx.x, bn = blockIdx.y, b = blockIdx.z;

    floatx4 acc[4][4];
#pragma unroll
    for (int i = 0; i < 4; i++)
#pragma unroll
        for (int j = 0; j < 4; j++) acc[i][j] = (floatx4){0.f, 0.f, 0.f, 0.f};

    const int c0 = tid, c1 = tid + 256;
    int t0c = bm * 128 + (c0 >> 2); if (t0c >= NV) t0c = NV - 1;
    int t1c = bm * 128 + (c1 >> 2); if (t1c >= NV) t1c = NV - 1;
    half_t* al0 = &As[c0 * 8]; half_t* al1 = &As[c1 * 8];
    half_t* bl0 = &Bs[c0 * 8]; half_t* bl1 = &Bs[c1 * 8];
    const int fr = (lane & 15) * 32 + (lane >> 4) * 8;

    for (int phase = 0; phase < 2; phase++) {
        const half_t* A = phase ? qb : kg;
        const size_t rowstart = phase ? (size_t)b * NT : (size_t)b * NV;
        const half_t* Bw = phase ? Fw : W2;
        const half_t* ag0 = A + (rowstart + t0c) * 512 + (c0 & 3) * 8;
        const half_t* ag1 = A + (rowstart + t1c) * 512 + (c1 & 3) * 8;
        const half_t* bg0 = Bw + (size_t)(bn * 128 + (c0 >> 2)) * 512 + (c0 & 3) * 8;
        const half_t* bg1 = Bw + (size_t)(bn * 128 + (c1 >> 2)) * 512 + (c1 & 3) * 8;

        for (int k0 = 0; k0 < 512; k0 += 32) {
            __syncthreads();
            gload16(ag0 + k0, al0);
            gload16(ag1 + k0, al1);
            gload16(bg0 + k0, bl0);
            gload16(bg1 + k0, bl1);
            __syncthreads();
            half8 a[4], bfr[4];
#pragma unroll
            for (int i = 0; i < 4; i++)
                a[i] = *(const half8*)&As[(wr + i * 16) * 32 + fr];
#pragma unroll
            for (int j = 0; j < 4; j++)
                bfr[j] = *(const half8*)&Bs[(wc + j * 16) * 32 + fr];
#pragma unroll
            for (int i = 0; i < 4; i++)
#pragma unroll
                for (int j = 0; j < 4; j++)
                    acc[i][j] = __builtin_amdgcn_mfma_f32_16x16x32_f16(
                        a[i], bfr[j], acc[i][j], 0, 0, 0);
        }
    }

    const int colbase = bn * 128 + wc + (lane & 15);
    const int rowbase = bm * 128 + wr + ((lane >> 4) << 2);
#pragma unroll
    for (int i = 0; i < 4; i++)
#pragma unroll
        for (int j = 0; j < 4; j++) {
            const int col = colbase + j * 16;
            const float bv = bias2[col];
#pragma unroll
            for (int r = 0; r < 4; r++) {
                const int t = rowbase + i * 16 + r;
                if (t < NV) {
                    const size_t idx = ((size_t)b * NV + t) * 512 + col;
                    out[idx] = acc[i][j][r] + bv + (float)vres[idx];
                }
            }
        }
}

// ---------------------------------------------------------------- launch
extern "C" void kernel_launch(void* const* d_in, const int* in_sizes, int n_in,
                              void* d_out, int out_size, void* d_ws, size_t ws_size,
                              hipStream_t stream)
{
    const float* verts  = (const float*)d_in[0];
    const float* imgf   = (const float*)d_in[1];
    const float* fc_w   = (const float*)d_in[2];
    const float* fc_b   = (const float*)d_in[3];
    const float* q_w    = (const float*)d_in[4];
    const float* q_b    = (const float*)d_in[5];
    const float* k_w    = (const float*)d_in[6];
    const float* k_b    = (const float*)d_in[7];
    const float* w_g    = (const float*)d_in[8];
    const float* proj_w = (const float*)d_in[9];
    const float* proj_b = (const float*)d_in[10];
    const float* fin_w  = (const float*)d_in[11];
    const float* fin_b  = (const float*)d_in[12];

    char* ws = (char*)d_ws;
    size_t off = 0;
    auto alloc = [&](size_t bytes) -> void* {
        void* p = ws + off;
        off += (bytes + 255) & ~(size_t)255;
        return p;
    };
    half_t* vb    = (half_t*)alloc((size_t)MV * D_ * 2);
    half_t* ib    = (half_t*)alloc((size_t)MI * IMGD * 2);
    half_t* fcwb  = (half_t*)alloc((size_t)D_ * IMGD * 2);
    half_t* qwb   = (half_t*)alloc((size_t)D_ * D_ * 2);
    half_t* kwb   = (half_t*)alloc((size_t)D_ * D_ * 2);
    half_t* fwb   = (half_t*)alloc((size_t)D_ * D_ * 2);
    half_t* pwtb  = (half_t*)alloc((size_t)D_ * D_ * 2);
    half_t* w2    = (half_t*)alloc((size_t)D_ * D_ * 2);
    half_t* imgp  = (half_t*)alloc((size_t)MI * D_ * 2);
    half_t* qb    = (half_t*)alloc((size_t)MQ * D_ * 2);
    half_t* kg    = (half_t*)alloc((size_t)MV * D_ * 2);
    float*  araw  = (float*)alloc((size_t)MQ * 4);
    float*  g     = (float*)alloc((size_t)B_ * D_ * 4);
    float*  bias2 = (float*)alloc((size_t)D_ * 4);

    convert_all<<<4096, 256, 0, stream>>>(verts, imgf, fc_w, q_w, k_w, fin_w,
                                          vb, ib, fcwb, qwb, kwb, fwb);
    transpose_pw<<<512, 256, 0, stream>>>(proj_w, pwtb);
    make_bias2<<<2, 256, 0, stream>>>(proj_b, fin_w, fin_b, bias2);
    // W2 = F @ P : [f,d], shared by all batches
    gemm_bt<4><<<dim3(4, 4), 256, 0, stream>>>(fwb, pwtb, nullptr, D_, w2);
    // imgp = img_f @ fc_w^T + fc_b
    gemm_bt<0><<<dim3(MI / 128, 4), 256, 0, stream>>>(ib, fcwb, fc_b, IMGD, imgp);
    // q over vert rows and img rows (l2norm + logits fused)
    nrm_gemm<0, NV, 0><<<MV / 64, 256, 0, stream>>>(
        vb, qwb, q_b, w_g, qb, araw);
    nrm_gemm<0, NI, NV><<<MI / 64, 256, 0, stream>>>(
        imgp, qwb, q_b, w_g, qb, araw);
    softmax_w<<<B_, 256, 0, stream>>>(araw, g);
    accum_g<<<dim3(8, B_), 256, 0, stream>>>(araw, qb, g);
    // kg = l2norm(verts @ k_w^T + k_b) * g   (needs g, hence after accum_g)
    nrm_gemm<1, NV, 0><<<MV / 64, 256, 0, stream>>>(
        vb, kwb, k_b, g, kg, nullptr);
    // out = vb + bias2 + kg @ W2^T + q @ F^T
    final2<<<dim3(13, 4, B_), 256, 0, stream>>>(
        kg, qb, w2, fwb, bias2, vb, (float*)d_out);
}

// Round 4
// 632.023 us; speedup vs baseline: 1.2583x; 1.0125x over previous
//
#include <hip/hip_runtime.h>

#define B_    32
#define NV    1556
#define NI    256
#define NT    1812          // NV + NI
#define D_    512
#define IMGD  2048
#define MV    (B_*NV)       // 49792 = 389*128
#define MI    (B_*NI)       // 8192  = 64*128
#define MQ    (B_*NT)       // 57984
#define SCALE_ 0.08838834764831845f   // (512/4)^-0.5

typedef _Float16 half_t;
typedef __attribute__((ext_vector_type(4))) _Float16 half4;
typedef __attribute__((ext_vector_type(8))) _Float16 half8;
typedef __attribute__((ext_vector_type(4))) float floatx4;

__device__ __forceinline__ void gload16(const void* g, void* l) {
    __builtin_amdgcn_global_load_lds(
        (const __attribute__((address_space(1))) void*)g,
        (__attribute__((address_space(3))) void*)l, 16, 0, 0);
}

// ---------------------------------------------------------------- convert
__global__ __launch_bounds__(256) void convert_all(
    const float* __restrict__ verts, const float* __restrict__ img,
    const float* __restrict__ w2, const float* __restrict__ w3,
    const float* __restrict__ w4, const float* __restrict__ w5,
    half_t* __restrict__ o0, half_t* __restrict__ o1, half_t* __restrict__ o2,
    half_t* __restrict__ o3, half_t* __restrict__ o4, half_t* __restrict__ o5)
{
    const long E0 = (long)MV * D_;
    const long E1 = (long)MI * IMGD;
    const long E2 = (long)D_ * IMGD;
    const long E3 = (long)D_ * D_;
    const long total4 = (E0 + E1 + E2 + 3 * E3) / 4;
    for (long i = blockIdx.x * (long)blockDim.x + threadIdx.x; i < total4;
         i += (long)gridDim.x * blockDim.x) {
        long e = i * 4;
        const float* s; half_t* d;
        if (e < E0)              { s = verts; d = o0; }
        else if ((e -= E0) < E1) { s = img;   d = o1; }
        else if ((e -= E1) < E2) { s = w2;    d = o2; }
        else if ((e -= E2) < E3) { s = w3;    d = o3; }
        else if ((e -= E3) < E3) { s = w4;    d = o4; }
        else                     { e -= E3; s = w5; d = o5; }
        float4 x = *(const float4*)(s + e);
        half4 h = { (half_t)x.x, (half_t)x.y, (half_t)x.z, (half_t)x.w };
        *(half4*)(d + e) = h;
    }
}

// pwt[d,e] = proj_w[e,d]  (f16)
__global__ __launch_bounds__(256) void transpose_pw(
    const float* __restrict__ P, half_t* __restrict__ pwt)
{
    const int n = blockIdx.x;
    for (int d = threadIdx.x; d < 512; d += 256)
        pwt[(size_t)n * 512 + d] = (half_t)P[(size_t)d * 512 + n];
}

// bias2[f] = sum_d pb[d]*F[f,d] + fb[f]
__global__ __launch_bounds__(256) void make_bias2(
    const float* __restrict__ pb, const float* __restrict__ F,
    const float* __restrict__ fb, float* __restrict__ bias2)
{
    const int n = blockIdx.x * 256 + threadIdx.x;
    float s = fb[n];
    for (int d = 0; d < 512; d++) s += pb[d] * F[(size_t)n * 512 + d];
    bias2[n] = s;
}

// ---------------------------------------------------------------- basic 128x128 GEMM
template<int MODE>
__global__ __launch_bounds__(256) void gemm_bt(
    const half_t* __restrict__ A, const half_t* __restrict__ Bw,
    const float* __restrict__ bias, int K, half_t* __restrict__ Ch)
{
    __shared__ __align__(16) half_t As[128 * 32];
    __shared__ __align__(16) half_t Bs[128 * 32];
    const int tid  = threadIdx.x;
    const int lane = tid & 63;
    const int wave = tid >> 6;
    const int wr = (wave >> 1) * 64;
    const int wc = (wave & 1) * 64;
    const int bm = blockIdx.x, bn = blockIdx.y;

    floatx4 acc[4][4];
#pragma unroll
    for (int i = 0; i < 4; i++)
#pragma unroll
        for (int j = 0; j < 4; j++) acc[i][j] = (floatx4){0.f, 0.f, 0.f, 0.f};

    const int c0 = tid, c1 = tid + 256;
    const half_t* ag0 = A  + (size_t)(bm * 128 + (c0 >> 2)) * K + (c0 & 3) * 8;
    const half_t* ag1 = A  + (size_t)(bm * 128 + (c1 >> 2)) * K + (c1 & 3) * 8;
    const half_t* bg0 = Bw + (size_t)(bn * 128 + (c0 >> 2)) * K + (c0 & 3) * 8;
    const half_t* bg1 = Bw + (size_t)(bn * 128 + (c1 >> 2)) * K + (c1 & 3) * 8;
    half_t* al0 = &As[c0 * 8]; half_t* al1 = &As[c1 * 8];
    half_t* bl0 = &Bs[c0 * 8]; half_t* bl1 = &Bs[c1 * 8];
    const int fr = (lane & 15) * 32 + (lane >> 4) * 8;

    for (int k0 = 0; k0 < K; k0 += 32) {
        __syncthreads();
        gload16(ag0 + k0, al0);
        gload16(ag1 + k0, al1);
        gload16(bg0 + k0, bl0);
        gload16(bg1 + k0, bl1);
        __syncthreads();
        half8 a[4], b[4];
#pragma unroll
        for (int i = 0; i < 4; i++)
            a[i] = *(const half8*)&As[(wr + i * 16) * 32 + fr];
#pragma unroll
        for (int j = 0; j < 4; j++)
            b[j] = *(const half8*)&Bs[(wc + j * 16) * 32 + fr];
#pragma unroll
        for (int i = 0; i < 4; i++)
#pragma unroll
            for (int j = 0; j < 4; j++)
                acc[i][j] = __builtin_amdgcn_mfma_f32_16x16x32_f16(
                    a[i], b[j], acc[i][j], 0, 0, 0);
    }

    const int colbase = bn * 128 + wc + (lane & 15);
    const int rowbase = bm * 128 + wr + ((lane >> 4) << 2);
#pragma unroll
    for (int i = 0; i < 4; i++)
#pragma unroll
        for (int j = 0; j < 4; j++) {
            const int col = colbase + j * 16;
            const float bv = (MODE == 0) ? bias[col] : 0.f;
#pragma unroll
            for (int r = 0; r < 4; r++) {
                const int grow = rowbase + i * 16 + r;
                Ch[(size_t)grow * D_ + col] = (half_t)(acc[i][j][r] + bv);
            }
        }
}

// ---------------------------------------------------------------- full-N GEMM (128 rows x 512 cols)
template<int MODE, int TA, int COFF>
__global__ __launch_bounds__(512, 2) void gemm_fn(
    const half_t* __restrict__ A, const half_t* __restrict__ A2,
    const half_t* __restrict__ Bw, const half_t* __restrict__ Bw2,
    const float* __restrict__ bias, const float* __restrict__ aux,
    const half_t* __restrict__ vres, half_t* __restrict__ outp,
    float* __restrict__ fout)
{
    __shared__ __align__(16) half_t As[128 * 32];   // 8 KB
    __shared__ __align__(16) half_t Bs[512 * 32];   // 32 KB
    __shared__ float red[4][128];
    __shared__ float scale_l[128];

    const int tid = threadIdx.x, lane = tid & 63, wave = tid >> 6;
    const int rg = wave >> 2, cg = wave & 3;
    const int quad = lane >> 4, l15 = lane & 15;
    const int bm = blockIdx.x;

    const int arow = tid >> 2, akp = (tid & 3) * 8;
    const int gr_a = bm * 128 + arow;
    const half_t* ag0 = A + (size_t)gr_a * 512 + akp;
    const half_t* ag1 = nullptr;
    if (MODE == 3) {
        const int b = gr_a / NV, t = gr_a - b * NV;
        ag1 = A2 + ((size_t)b * NT + t) * 512 + akp;
    }
    half_t* al = &As[tid * 8];
    size_t boff[4];
#pragma unroll
    for (int s = 0; s < 4; s++)
        boff[s] = (size_t)((tid >> 2) + 128 * s) * 512 + akp;

    floatx4 acc[4][8];
#pragma unroll
    for (int i = 0; i < 4; i++)
#pragma unroll
        for (int j = 0; j < 8; j++) acc[i][j] = (floatx4){0.f, 0.f, 0.f, 0.f};

    const int nphase = (MODE == 3) ? 2 : 1;
    for (int ph = 0; ph < nphase; ph++) {
        const half_t* ag = (ph == 0) ? ag0 : ag1;
        const half_t* bb = (ph == 0) ? Bw : Bw2;
        for (int k0 = 0; k0 < 512; k0 += 32) {
            __syncthreads();
            gload16(ag + k0, al);
#pragma unroll
            for (int s = 0; s < 4; s++)
                gload16(bb + boff[s] + k0, &Bs[(tid + 512 * s) * 8]);
            __syncthreads();
            half8 a[4], b[8];
#pragma unroll
            for (int i = 0; i < 4; i++)
                a[i] = *(const half8*)&As[(rg * 64 + i * 16 + l15) * 32 + quad * 8];
#pragma unroll
            for (int j = 0; j < 8; j++)
                b[j] = *(const half8*)&Bs[(cg * 128 + j * 16 + l15) * 32 + quad * 8];
#pragma unroll
            for (int i = 0; i < 4; i++)
#pragma unroll
                for (int j = 0; j < 8; j++)
                    acc[i][j] = __builtin_amdgcn_mfma_f32_16x16x32_f16(
                        a[i], b[j], acc[i][j], 0, 0, 0);
        }
    }

    if (MODE == 3) {
#pragma unroll
        for (int j = 0; j < 8; j++) {
            const int col = cg * 128 + j * 16 + l15;
            const float bv = bias[col];
#pragma unroll
            for (int i = 0; i < 4; i++)
#pragma unroll
                for (int r = 0; r < 4; r++) {
                    const int gr = bm * 128 + rg * 64 + i * 16 + quad * 4 + r;
                    const size_t idx = (size_t)gr * 512 + col;
                    fout[idx] = acc[i][j][r] + bv + (float)vres[idx];
                }
        }
        return;
    }

    // ---- bias + row sum-of-squares
    float ssq[4][4];
#pragma unroll
    for (int i = 0; i < 4; i++)
#pragma unroll
        for (int r = 0; r < 4; r++) ssq[i][r] = 0.f;
#pragma unroll
    for (int j = 0; j < 8; j++) {
        const float bv = bias[cg * 128 + j * 16 + l15];
#pragma unroll
        for (int i = 0; i < 4; i++)
#pragma unroll
            for (int r = 0; r < 4; r++) {
                float v = acc[i][j][r] + bv;
                acc[i][j][r] = v;
                ssq[i][r] += v * v;
            }
    }
#pragma unroll
    for (int i = 0; i < 4; i++)
#pragma unroll
        for (int r = 0; r < 4; r++)
#pragma unroll
            for (int m = 1; m < 16; m <<= 1)
                ssq[i][r] += __shfl_xor(ssq[i][r], m, 64);
    if (l15 == 0) {
#pragma unroll
        for (int i = 0; i < 4; i++)
#pragma unroll
            for (int r = 0; r < 4; r++)
                red[cg][rg * 64 + i * 16 + quad * 4 + r] = ssq[i][r];
    }
    __syncthreads();
    if (tid < 128)
        scale_l[tid] = 1.f / fmaxf(
            sqrtf(red[0][tid] + red[1][tid] + red[2][tid] + red[3][tid]), 1e-12f);
    __syncthreads();

    float sc[4][4];
    int rowb[4][4], rowt[4][4];
#pragma unroll
    for (int i = 0; i < 4; i++)
#pragma unroll
        for (int r = 0; r < 4; r++) {
            const int li = rg * 64 + i * 16 + quad * 4 + r;
            sc[i][r] = scale_l[li];
            const int gr = bm * 128 + li;
            const int b = gr / TA;
            rowb[i][r] = b;
            rowt[i][r] = gr - b * TA;
        }

    if (MODE == 1) {
        size_t ro[4][4];
        float dot[4][4];
#pragma unroll
        for (int i = 0; i < 4; i++)
#pragma unroll
            for (int r = 0; r < 4; r++) {
                ro[i][r] = ((size_t)rowb[i][r] * NT + COFF + rowt[i][r]) * 512;
                dot[i][r] = 0.f;
            }
#pragma unroll
        for (int j = 0; j < 8; j++) {
            const int col = cg * 128 + j * 16 + l15;
            const float wgv = aux[col];
#pragma unroll
            for (int i = 0; i < 4; i++)
#pragma unroll
                for (int r = 0; r < 4; r++) {
                    const float qn = acc[i][j][r] * sc[i][r];
                    outp[ro[i][r] + col] = (half_t)qn;
                    dot[i][r] += qn * wgv;
                }
        }
#pragma unroll
        for (int i = 0; i < 4; i++)
#pragma unroll
            for (int r = 0; r < 4; r++)
#pragma unroll
                for (int m = 1; m < 16; m <<= 1)
                    dot[i][r] += __shfl_xor(dot[i][r], m, 64);
        if (l15 == 0) {
#pragma unroll
            for (int i = 0; i < 4; i++)
#pragma unroll
                for (int r = 0; r < 4; r++)
                    red[cg][rg * 64 + i * 16 + quad * 4 + r] = dot[i][r];
        }
        __syncthreads();
        if (tid < 128) {
            const int gr = bm * 128 + tid;
            const int b = gr / TA, t = gr - b * TA;
            fout[b * NT + COFF + t] = SCALE_ *
                (red[0][tid] + red[1][tid] + red[2][tid] + red[3][tid]);
        }
    } else {
        // MODE 2: kg = l2norm(k) * g[b,col]
#pragma unroll
        for (int j = 0; j < 8; j++) {
            const int col = cg * 128 + j * 16 + l15;
#pragma unroll
            for (int i = 0; i < 4; i++)
#pragma unroll
                for (int r = 0; r < 4; r++) {
                    const int gr = bm * 128 + rg * 64 + i * 16 + quad * 4 + r;
                    const float gv = aux[rowb[i][r] * 512 + col];
                    outp[(size_t)gr * 512 + col] =
                        (half_t)(acc[i][j][r] * sc[i][r] * gv);
                }
        }
    }
}

// ---------------------------------------------------------------- softmax (per batch) + zero g
__global__ __launch_bounds__(256) void softmax_w(
    float* __restrict__ araw, float* __restrict__ g)
{
    const int b = blockIdx.x;
    float* a = araw + (size_t)b * NT;
    g[b * D_ + threadIdx.x] = 0.f;
    g[b * D_ + 256 + threadIdx.x] = 0.f;
    __shared__ float red[8];
    const int lane = threadIdx.x & 63, wave = threadIdx.x >> 6;
    float m = -1e30f;
    for (int i = threadIdx.x; i < NT; i += 256) m = fmaxf(m, a[i]);
#pragma unroll
    for (int off = 32; off > 0; off >>= 1) m = fmaxf(m, __shfl_xor(m, off, 64));
    if (lane == 0) red[wave] = m;
    __syncthreads();
    m = fmaxf(fmaxf(red[0], red[1]), fmaxf(red[2], red[3]));
    float s = 0.f;
    for (int i = threadIdx.x; i < NT; i += 256) s += expf(a[i] - m);
#pragma unroll
    for (int off = 32; off > 0; off >>= 1) s += __shfl_xor(s, off, 64);
    if (lane == 0) red[4 + wave] = s;
    __syncthreads();
    s = red[4] + red[5] + red[6] + red[7];
    const float inv = 1.0f / s;
    for (int i = threadIdx.x; i < NT; i += 256) a[i] = expf(a[i] - m) * inv;
}

// ---------------------------------------------------------------- g = sum_n a_n * q_n
__global__ __launch_bounds__(256) void accum_g(
    const float* __restrict__ w, const half_t* __restrict__ qb, float* __restrict__ g)
{
    __shared__ float red[4][512];
    const int b = blockIdx.y, tid = threadIdx.x, lane = tid & 63, wave = tid >> 6;
    const int t0 = blockIdx.x * 227;
    const int t1 = (t0 + 227 < NT) ? t0 + 227 : NT;
    float a[8];
#pragma unroll
    for (int r = 0; r < 8; r++) a[r] = 0.f;
    for (int n = t0 + wave; n < t1; n += 4) {
        const float wn = w[(size_t)b * NT + n];
        half8 v = *(const half8*)&qb[((size_t)b * NT + n) * 512 + lane * 8];
#pragma unroll
        for (int r = 0; r < 8; r++) a[r] += wn * (float)v[r];
    }
#pragma unroll
    for (int r = 0; r < 8; r++) red[wave][lane * 8 + r] = a[r];
    __syncthreads();
    for (int d = tid; d < 512; d += 256)
        atomicAdd(&g[b * 512 + d], red[0][d] + red[1][d] + red[2][d] + red[3][d]);
}

// ---------------------------------------------------------------- launch
extern "C" void kernel_launch(void* const* d_in, const int* in_sizes, int n_in,
                              void* d_out, int out_size, void* d_ws, size_t ws_size,
                              hipStream_t stream)
{
    const float* verts  = (const float*)d_in[0];
    const float* imgf   = (const float*)d_in[1];
    const float* fc_w   = (const float*)d_in[2];
    const float* fc_b   = (const float*)d_in[3];
    const float* q_w    = (const float*)d_in[4];
    const float* q_b    = (const float*)d_in[5];
    const float* k_w    = (const float*)d_in[6];
    const float* k_b    = (const float*)d_in[7];
    const float* w_g    = (const float*)d_in[8];
    const float* proj_w = (const float*)d_in[9];
    const float* proj_b = (const float*)d_in[10];
    const float* fin_w  = (const float*)d_in[11];
    const float* fin_b  = (const float*)d_in[12];

    char* ws = (char*)d_ws;
    size_t off = 0;
    auto alloc = [&](size_t bytes) -> void* {
        void* p = ws + off;
        off += (bytes + 255) & ~(size_t)255;
        return p;
    };
    half_t* vb    = (half_t*)alloc((size_t)MV * D_ * 2);
    half_t* ib    = (half_t*)alloc((size_t)MI * IMGD * 2);
    half_t* fcwb  = (half_t*)alloc((size_t)D_ * IMGD * 2);
    half_t* qwb   = (half_t*)alloc((size_t)D_ * D_ * 2);
    half_t* kwb   = (half_t*)alloc((size_t)D_ * D_ * 2);
    half_t* fwb   = (half_t*)alloc((size_t)D_ * D_ * 2);
    half_t* pwtb  = (half_t*)alloc((size_t)D_ * D_ * 2);
    half_t* w2    = (half_t*)alloc((size_t)D_ * D_ * 2);
    half_t* imgp  = (half_t*)alloc((size_t)MI * D_ * 2);
    half_t* qb    = (half_t*)alloc((size_t)MQ * D_ * 2);
    half_t* kg    = (half_t*)alloc((size_t)MV * D_ * 2);
    float*  araw  = (float*)alloc((size_t)MQ * 4);
    float*  g     = (float*)alloc((size_t)B_ * D_ * 4);
    float*  bias2 = (float*)alloc((size_t)D_ * 4);

    convert_all<<<4096, 256, 0, stream>>>(verts, imgf, fc_w, q_w, k_w, fin_w,
                                          vb, ib, fcwb, qwb, kwb, fwb);
    transpose_pw<<<512, 256, 0, stream>>>(proj_w, pwtb);
    make_bias2<<<2, 256, 0, stream>>>(proj_b, fin_w, fin_b, bias2);
    // W2 = F @ P
    gemm_bt<4><<<dim3(4, 4), 256, 0, stream>>>(fwb, pwtb, nullptr, D_, w2);
    // imgp = img_f @ fc_w^T + fc_b
    gemm_bt<0><<<dim3(MI / 128, 4), 256, 0, stream>>>(ib, fcwb, fc_b, IMGD, imgp);
    // q-hat over vert rows and img rows (full-N, l2norm + logits fused)
    gemm_fn<1, NV, 0><<<MV / 128, 512, 0, stream>>>(
        vb, nullptr, qwb, nullptr, q_b, w_g, nullptr, qb, araw);
    gemm_fn<1, NI, NV><<<MI / 128, 512, 0, stream>>>(
        imgp, nullptr, qwb, nullptr, q_b, w_g, nullptr, qb, araw);
    softmax_w<<<B_, 256, 0, stream>>>(araw, g);
    accum_g<<<dim3(8, B_), 256, 0, stream>>>(araw, qb, g);
    // kg = l2norm(verts @ k_w^T + k_b) * g
    gemm_fn<2, NV, 0><<<MV / 128, 512, 0, stream>>>(
        vb, nullptr, kwb, nullptr, k_b, g, nullptr, kg, nullptr);
    // out = vb + bias2 + kg @ W2^T + q-hat @ F^T
    gemm_fn<3, NV, 0><<<MV / 128, 512, 0, stream>>>(
        kg, qb, w2, fwb, bias2, nullptr, vb, nullptr, (float*)d_out);
}